// Round 1
// baseline (701.256 us; speedup 1.0000x reference)
//
#include <hip/hip_runtime.h>
#include <hip/hip_bf16.h>

#define DM 1024
#define NH 16
#define HD 64
#define BB 2
#define LLEN 2048
#define MR (BB*LLEN)   // 4096

typedef __attribute__((ext_vector_type(8))) short bf16x8;
typedef __attribute__((ext_vector_type(4))) float f32x4;

#define AS1(p) ((const __attribute__((address_space(1))) void*)(p))
#define AS3(p) ((__attribute__((address_space(3))) void*)(p))

__device__ __forceinline__ ushort f2bf(float x) {
    union { float f; unsigned u; } v; v.f = x;
    unsigned r = v.u + 0x7FFFu + ((v.u >> 16) & 1u);   // RNE
    return (ushort)(r >> 16);
}
__device__ __forceinline__ float bf2f(ushort x) {
    union { unsigned u; float f; } v; v.u = ((unsigned)x) << 16;
    return v.f;
}

// ---------------- fp32 -> bf16 converters ----------------
__global__ __launch_bounds__(256) void cvtX(const float* __restrict__ a,
                                            const float* __restrict__ b,
                                            const float* __restrict__ c,
                                            ushort* __restrict__ dst, int n) {
    const float* src = blockIdx.y == 0 ? a : (blockIdx.y == 1 ? b : c);
    ushort* d = dst + (size_t)blockIdx.y * n;
    int i = (blockIdx.x * 256 + threadIdx.x) * 4;
    float4 v = *(const float4*)(src + i);
    ushort4 o = make_ushort4(f2bf(v.x), f2bf(v.y), f2bf(v.z), f2bf(v.w));
    *(ushort4*)(d + i) = o;
}

__global__ __launch_bounds__(256) void cvtW(const float* __restrict__ w0,
                                            const float* __restrict__ w1,
                                            const float* __restrict__ w2,
                                            const float* __restrict__ w3,
                                            ushort* __restrict__ dst, int n) {
    const float* src = blockIdx.y == 0 ? w0 : (blockIdx.y == 1 ? w1 : (blockIdx.y == 2 ? w2 : w3));
    ushort* d = dst + (size_t)blockIdx.y * n;
    int i = (blockIdx.x * 256 + threadIdx.x) * 4;
    float4 v = *(const float4*)(src + i);
    ushort4 o = make_ushort4(f2bf(v.x), f2bf(v.y), f2bf(v.z), f2bf(v.w));
    *(ushort4*)(d + i) = o;
}

// ---------------- GEMM: C[M,N] = A[M,K](bf16) @ Bw[N,K](bf16)^T + bias ----------------
// 128x128 tile, BK=32, 256 threads (4 waves, 2x2 of 64x64), m97 structure.
template<typename OutT>
__global__ __launch_bounds__(256) void gemm_bt(
    const ushort* __restrict__ A, const ushort* __restrict__ Bw,
    OutT* __restrict__ Cc,
    const float* __restrict__ bias0, const float* __restrict__ bias1, const float* __restrict__ bias2,
    int M, int N, int K, long sA, long sB, long sC)
{
    __shared__ __attribute__((aligned(16))) ushort As[128 * 32];
    __shared__ __attribute__((aligned(16))) ushort Bs[128 * 32];
    const int tid = threadIdx.x;
    const int lane = tid & 63;
    const int wv = tid >> 6;
    const int wm = wv >> 1, wn = wv & 1;
    const int z = blockIdx.z;
    const ushort* Ab = A + (size_t)z * sA;
    const ushort* Bb = Bw + (size_t)z * sB;
    OutT* Cb = Cc + (size_t)z * sC;
    const float* bias = z == 0 ? bias0 : (z == 1 ? bias1 : bias2);
    const int m0 = blockIdx.x * 128;
    const int n0 = blockIdx.y * 128;
    const int l15 = lane & 15, l4 = lane >> 4;

    f32x4 acc[4][4] = {};
    const int nk = K >> 5;
    const int srow = tid >> 2;
    const int sblk = tid & 3;

    auto stage = [&](int kb) {
        int k0 = kb * 32;
#pragma unroll
        for (int r = 0; r < 2; ++r) {
            int row = r * 64 + srow;
            int s = (row >> 1) & 3;
            const ushort* ga = Ab + (size_t)(m0 + row) * K + k0 + ((sblk ^ s) * 8);
            __builtin_amdgcn_global_load_lds(AS1(ga), AS3(As + row * 32 + sblk * 8), 16, 0, 0);
            const ushort* gb = Bb + (size_t)(n0 + row) * K + k0 + ((sblk ^ s) * 8);
            __builtin_amdgcn_global_load_lds(AS1(gb), AS3(Bs + row * 32 + sblk * 8), 16, 0, 0);
        }
    };

    stage(0);
    for (int kb = 0; kb < nk; ++kb) {
        __syncthreads();
        bf16x8 af[4], bfr[4];
#pragma unroll
        for (int i = 0; i < 4; ++i) {
            int rowA = wm * 64 + i * 16 + l15;
            int sa = (rowA >> 1) & 3;
            af[i] = *(const bf16x8*)(As + rowA * 32 + ((l4 ^ sa) * 8));
            int rowB = wn * 64 + i * 16 + l15;
            int sb = (rowB >> 1) & 3;
            bfr[i] = *(const bf16x8*)(Bs + rowB * 32 + ((l4 ^ sb) * 8));
        }
#pragma unroll
        for (int i = 0; i < 4; ++i)
#pragma unroll
            for (int j = 0; j < 4; ++j)
                acc[i][j] = __builtin_amdgcn_mfma_f32_16x16x32_bf16(af[i], bfr[j], acc[i][j], 0, 0, 0);
        __syncthreads();
        if (kb + 1 < nk) stage(kb + 1);
    }
#pragma unroll
    for (int i = 0; i < 4; ++i) {
#pragma unroll
        for (int j = 0; j < 4; ++j) {
            int col = n0 + wn * 64 + j * 16 + l15;
            float bv = bias[col];
#pragma unroll
            for (int r = 0; r < 4; ++r) {
                int row = m0 + wm * 64 + i * 16 + l4 * 4 + r;
                float val = acc[i][j][r] + bv;
                if constexpr (sizeof(OutT) == 2) {
                    ((ushort*)Cb)[(size_t)row * N + col] = f2bf(val);
                } else {
                    Cb[(size_t)row * N + col] = val;
                }
            }
        }
    }
}

// ---------------- RoPE + head transpose for Q and K ----------------
// Yq/Yk: (B*L, 1024) bf16 pre-RoPE. Out: Qr/Kr (B,H,L,64) bf16, RoPE applied.
__global__ __launch_bounds__(256) void rope_qk(const ushort* __restrict__ Yq,
                                               const ushort* __restrict__ Yk,
                                               const float* __restrict__ pe,
                                               ushort* __restrict__ Qr,
                                               ushort* __restrict__ Kr) {
    int idx = blockIdx.x * 256 + threadIdx.x;      // B*L*H*32 = 2^21 threads
    int t = idx & 31;
    int h = (idx >> 5) & 15;
    int lq = (idx >> 9) & 2047;
    int b = idx >> 20;
    size_t srcoff = ((size_t)(b * LLEN + lq)) * DM + h * 64 + 2 * t;
    float2 cs = *(const float2*)(pe + (size_t)lq * 64 + 2 * t);   // cos = pe[2t], sin = pe[2t+1]
    unsigned yq = *(const unsigned*)(Yq + srcoff);
    unsigned yk = *(const unsigned*)(Yk + srcoff);
    float qe = bf2f((ushort)(yq & 0xffff)), qo = bf2f((ushort)(yq >> 16));
    float ke = bf2f((ushort)(yk & 0xffff)), ko = bf2f((ushort)(yk >> 16));
    size_t dst = ((size_t)(b * NH + h) * LLEN + lq) * 64;
    Qr[dst + t]      = f2bf(qe * cs.x - qo * cs.y);
    Qr[dst + 32 + t] = f2bf(qe * cs.y + qo * cs.x);
    Kr[dst + t]      = f2bf(ke * cs.x - ko * cs.y);
    Kr[dst + 32 + t] = f2bf(ke * cs.y + ko * cs.x);
}

// ---------------- V transpose: Yv (B*L,1024) bf16 -> Vt (B,H,64,L) bf16 ----------------
__global__ __launch_bounds__(256) void vtrans(const ushort* __restrict__ Yv, ushort* __restrict__ Vt) {
    __shared__ __attribute__((aligned(16))) ushort Vs[64 * 66];   // Vs[d][l], pad 66
    int tid = threadIdx.x;
    int lb = blockIdx.x * 64;
    int bh = blockIdx.y;
    int b = bh >> 4, h = bh & 15;
#pragma unroll
    for (int p = 0; p < 2; ++p) {
        int lr = p * 32 + (tid >> 3);
        int cb = tid & 7;
        bf16x8 v = *(const bf16x8*)(Yv + (size_t)(b * LLEN + lb + lr) * DM + h * 64 + cb * 8);
#pragma unroll
        for (int j = 0; j < 8; ++j)
            Vs[(cb * 8 + j) * 66 + lr] = (ushort)v[j];
    }
    __syncthreads();
    int d = tid >> 2, part = tid & 3;
    unsigned w[8];
#pragma unroll
    for (int i = 0; i < 8; ++i) {
        unsigned lo = Vs[d * 66 + part * 16 + 2 * i];
        unsigned hi = Vs[d * 66 + part * 16 + 2 * i + 1];
        w[i] = lo | (hi << 16);
    }
    size_t dst = ((size_t)(bh * 64 + d)) * LLEN + lb + part * 16;
    uint4 o0 = make_uint4(w[0], w[1], w[2], w[3]);
    uint4 o1 = make_uint4(w[4], w[5], w[6], w[7]);
    *(uint4*)(Vt + dst) = o0;
    *(uint4*)(Vt + dst + 8) = o1;
}

// ---------------- Flash attention with ALiBi ----------------
// grid (L/32, NH), 256 threads = 4 waves. wave w: batch b=w>>1, q-rows qb = bx*32 + (w&1)*16.
// Both batches in one block share the same alibi rows (L1 reuse).
__global__ __launch_bounds__(256) void attn(
    const ushort* __restrict__ Qr, const ushort* __restrict__ Kr, const ushort* __restrict__ Vt,
    const float* __restrict__ alibi, ushort* __restrict__ Abuf)
{
    __shared__ __attribute__((aligned(16))) ushort Ps[4][16 * 72];   // per-wave P tile, pad 72
    const float SCALE = 0.125f;
    int tid = threadIdx.x, lane = tid & 63, w = tid >> 6;
    int l15 = lane & 15, l4 = lane >> 4;
    int b = w >> 1, wq = w & 1;
    int h = blockIdx.y;
    int qb = blockIdx.x * 32 + wq * 16;
    int bh = b * NH + h;

    const ushort* Qb = Qr + ((size_t)bh * LLEN) * 64;
    const ushort* Kb = Kr + ((size_t)bh * LLEN) * 64;
    const ushort* Vb = Vt + ((size_t)bh * 64) * LLEN;
    const float* ab = alibi + (size_t)h * LLEN * LLEN;

    bf16x8 qf0 = *(const bf16x8*)(Qb + (size_t)(qb + l15) * 64 + l4 * 8);
    bf16x8 qf1 = *(const bf16x8*)(Qb + (size_t)(qb + l15) * 64 + 32 + l4 * 8);

    f32x4 O[4] = {};
    float mreg[4] = {-1e30f, -1e30f, -1e30f, -1e30f};
    float lreg[4] = {0.f, 0.f, 0.f, 0.f};
    ushort* Pw = &Ps[w][0];

    for (int kb = 0; kb < LLEN; kb += 64) {
        // ---- S = Q K^T (4 tiles of 16x16 along k) ----
        f32x4 s[4];
#pragma unroll
        for (int t = 0; t < 4; ++t) {
            const ushort* kr = Kb + (size_t)(kb + t * 16 + l15) * 64;
            bf16x8 kf0 = *(const bf16x8*)(kr + l4 * 8);
            bf16x8 kf1 = *(const bf16x8*)(kr + 32 + l4 * 8);
            f32x4 zz = {};
            zz = __builtin_amdgcn_mfma_f32_16x16x32_bf16(qf0, kf0, zz, 0, 0, 0);
            s[t] = __builtin_amdgcn_mfma_f32_16x16x32_bf16(qf1, kf1, zz, 0, 0, 0);
        }
        // ---- scale + alibi ----
        float sv[4][4];
#pragma unroll
        for (int t = 0; t < 4; ++t) {
            const float* ar = ab + (size_t)(qb + l4 * 4) * LLEN + kb + t * 16 + l15;
#pragma unroll
            for (int r = 0; r < 4; ++r)
                sv[t][r] = s[t][r] * SCALE + ar[(size_t)r * LLEN];
        }
        // ---- online softmax: row max / rescale / exp / row sum ----
        float mnew[4], fac[4];
#pragma unroll
        for (int r = 0; r < 4; ++r) {
            float mx = fmaxf(fmaxf(sv[0][r], sv[1][r]), fmaxf(sv[2][r], sv[3][r]));
            mx = fmaxf(mx, __shfl_xor(mx, 1));
            mx = fmaxf(mx, __shfl_xor(mx, 2));
            mx = fmaxf(mx, __shfl_xor(mx, 4));
            mx = fmaxf(mx, __shfl_xor(mx, 8));
            mnew[r] = fmaxf(mreg[r], mx);
            fac[r] = __expf(mreg[r] - mnew[r]);
            mreg[r] = mnew[r];
        }
#pragma unroll
        for (int r = 0; r < 4; ++r) {
            float rs = 0.f;
#pragma unroll
            for (int t = 0; t < 4; ++t) {
                float p = __expf(sv[t][r] - mreg[r]);
                sv[t][r] = p;
                rs += p;
            }
            rs += __shfl_xor(rs, 1);
            rs += __shfl_xor(rs, 2);
            rs += __shfl_xor(rs, 4);
            rs += __shfl_xor(rs, 8);
            lreg[r] = lreg[r] * fac[r] + rs;
        }
        // ---- P -> LDS (bf16), rescale O ----
#pragma unroll
        for (int t = 0; t < 4; ++t)
#pragma unroll
            for (int r = 0; r < 4; ++r)
                Pw[(l4 * 4 + r) * 72 + t * 16 + l15] = f2bf(sv[t][r]);
#pragma unroll
        for (int dt = 0; dt < 4; ++dt)
#pragma unroll
            for (int r = 0; r < 4; ++r)
                O[dt][r] *= fac[r];
        // ---- P as A-fragments, PV ----
        bf16x8 pf0 = *(const bf16x8*)(Pw + l15 * 72 + l4 * 8);
        bf16x8 pf1 = *(const bf16x8*)(Pw + l15 * 72 + 32 + l4 * 8);
#pragma unroll
        for (int dt = 0; dt < 4; ++dt) {
            const ushort* vr = Vb + (size_t)(dt * 16 + l15) * LLEN + kb;
            bf16x8 vf0 = *(const bf16x8*)(vr + l4 * 8);
            bf16x8 vf1 = *(const bf16x8*)(vr + 32 + l4 * 8);
            O[dt] = __builtin_amdgcn_mfma_f32_16x16x32_bf16(pf0, vf0, O[dt], 0, 0, 0);
            O[dt] = __builtin_amdgcn_mfma_f32_16x16x32_bf16(pf1, vf1, O[dt], 0, 0, 0);
        }
    }
    // ---- epilogue: divide by l, write to (B*L, 1024) bf16 ----
#pragma unroll
    for (int dt = 0; dt < 4; ++dt)
#pragma unroll
        for (int r = 0; r < 4; ++r) {
            int q = qb + l4 * 4 + r;
            float val = O[dt][r] / lreg[r];
            Abuf[(size_t)(b * LLEN + q) * DM + h * 64 + dt * 16 + l15] = f2bf(val);
        }
}

extern "C" void kernel_launch(void* const* d_in, const int* in_sizes, int n_in,
                              void* d_out, int out_size, void* d_ws, size_t ws_size,
                              hipStream_t stream) {
    const float* query = (const float*)d_in[0];
    const float* key_  = (const float*)d_in[1];
    const float* value = (const float*)d_in[2];
    const float* alibi = (const float*)d_in[3];
    const float* pose  = (const float*)d_in[4];
    const float* Wq    = (const float*)d_in[5];
    const float* bq    = (const float*)d_in[6];
    const float* Wk    = (const float*)d_in[7];
    const float* bk    = (const float*)d_in[8];
    const float* Wv    = (const float*)d_in[9];
    const float* bv    = (const float*)d_in[10];
    const float* Wo    = (const float*)d_in[11];
    const float* bo    = (const float*)d_in[12];

    ushort* Xbf  = (ushort*)d_ws;                         // 3 * 4M bf16
    ushort* Wbf  = Xbf + 3UL * MR * DM;                   // 4 * 1M bf16
    ushort* Ybf  = Wbf + 4UL * DM * DM;                   // 3 * 4M bf16
    ushort* Qr   = Ybf + 3UL * MR * DM;                   // 4M
    ushort* Kr   = Qr + (size_t)BB * NH * LLEN * HD;      // 4M
    ushort* Vt   = Kr + (size_t)BB * NH * LLEN * HD;      // 4M
    ushort* Abuf = Vt + (size_t)BB * NH * LLEN * HD;      // 4M

    cvtX<<<dim3(4096, 3), 256, 0, stream>>>(query, key_, value, Xbf, MR * DM);
    cvtW<<<dim3(1024, 4), 256, 0, stream>>>(Wq, Wk, Wv, Wo, Wbf, DM * DM);

    gemm_bt<ushort><<<dim3(32, 8, 3), 256, 0, stream>>>(
        Xbf, Wbf, Ybf, bq, bk, bv, MR, DM, DM,
        (long)MR * DM, (long)DM * DM, (long)MR * DM);

    rope_qk<<<8192, 256, 0, stream>>>(Ybf, Ybf + (size_t)MR * DM, pose, Qr, Kr);
    vtrans<<<dim3(32, 32), 256, 0, stream>>>(Ybf + 2UL * MR * DM, Vt);

    attn<<<dim3(LLEN / 32, NH), 256, 0, stream>>>(Qr, Kr, Vt, alibi, Abuf);

    gemm_bt<float><<<dim3(32, 8, 1), 256, 0, stream>>>(
        Abuf, Wbf + 3UL * DM * DM, (float*)d_out, bo, bo, bo, MR, DM, DM, 0, 0, 0);
}